// Round 10
// baseline (191.664 us; speedup 1.0000x reference)
//
#include <hip/hip_runtime.h>
#include <hip/hip_fp16.h>

#define NN 40000
#define NE 640000
#define F 128
#define NG 64
#define SCAN_NB 157  // ceil(40000/256)
#define GEMM_NB 625  // NN/64

typedef _Float16 f16x8 __attribute__((ext_vector_type(8)));
typedef float f32x4 __attribute__((ext_vector_type(4)));

union U4H {
    uint4 u;
    f16x8 h;
};

// ---------------- init: zero deg/pooled/slabs + graph bounds + W fp16 prep ----------------
__global__ __launch_bounds__(256) void k_init(const int* __restrict__ batch, int* __restrict__ deg,
                                              float* __restrict__ pooled, float* __restrict__ slabs,
                                              int* __restrict__ gstart, int* __restrict__ gend,
                                              const float* __restrict__ W1, const float* __restrict__ W2,
                                              _Float16* __restrict__ img1, _Float16* __restrict__ img2) {
    int i = blockIdx.x * 256 + threadIdx.x;
    if (i < NN) {
        deg[i] = 0;
        int g = batch[i];
        if (i == 0 || batch[i - 1] != g) gstart[g] = i;
        if (i == NN - 1 || batch[i + 1] != g) gend[g] = i + 1;
    }
    if (i < NG * F) pooled[i] = 0.f;
    if (i < 32768) {
        slabs[i] = 0.f;  // S1,Q1,S2,Q2 (4 x 8192)
        // W prep: fp16 round, transposed + XOR-swizzled image (A is split exactly; only W rounds)
        const float* W = (i < 16384) ? W1 : W2;
        _Float16* img = (i < 16384) ? img1 : img2;
        int j = i & 16383;
        int k = j >> 7, c = j & 127;
        int idx = (c * 128 + k) ^ ((c & 7) << 3);
        img[idx] = (_Float16)W[j];
    }
}

// ---------------- degree histogram ----------------
__global__ __launch_bounds__(256) void k_deg(const int* __restrict__ col, int* __restrict__ deg) {
    int e = blockIdx.x * 256 + threadIdx.x;
    if (e < NE) atomicAdd(&deg[col[e]], 1);
}

// ---------------- scan phase 1: per-block sums ----------------
__global__ __launch_bounds__(256) void k_scan1(const int* __restrict__ deg, int* __restrict__ partial) {
    __shared__ int sp[256];
    int t = threadIdx.x;
    int i = blockIdx.x * 256 + t;
    sp[t] = (i < NN) ? deg[i] : 0;
    __syncthreads();
#pragma unroll
    for (int off = 128; off > 0; off >>= 1) {
        if (t < off) sp[t] += sp[t + off];
        __syncthreads();
    }
    if (t == 0) partial[blockIdx.x] = sp[0];
}

// ---------------- scan phase 2 (fused): every block scans partials + local scan ----------------
__global__ __launch_bounds__(256) void k_scan3(const int* __restrict__ deg, const int* __restrict__ partial,
                                               int* __restrict__ indptr, int* __restrict__ cursor,
                                               float* __restrict__ dinv) {
    __shared__ int sp[256];
    __shared__ int sd[256];
    int t = threadIdx.x;
    sp[t] = (t < SCAN_NB) ? partial[t] : 0;
    __syncthreads();
#pragma unroll
    for (int off = 1; off < 256; off <<= 1) {
        int add = (t >= off) ? sp[t - off] : 0;
        __syncthreads();
        sp[t] += add;
        __syncthreads();
    }
    int bid = blockIdx.x;
    if (bid == 0 && t == 0) indptr[NN] = sp[SCAN_NB - 1];
    int bsum = (bid == 0) ? 0 : sp[bid - 1];

    int i = bid * 256 + t;
    int d = (i < NN) ? deg[i] : 0;
    sd[t] = d;
    __syncthreads();
#pragma unroll
    for (int off = 1; off < 256; off <<= 1) {
        int add = (t >= off) ? sd[t - off] : 0;
        __syncthreads();
        sd[t] += add;
        __syncthreads();
    }
    if (i < NN) {
        int excl = bsum + sd[t] - d;
        indptr[i] = excl;
        cursor[i] = excl;
        dinv[i] = rsqrtf((float)(d + 1));
    }
}

// ---------------- FAT kernel: blocks 0..624 = layer-1 MFMA GEMM; blocks 625.. = CSR fill ----------------
// GEMM: G16[r*128+c] = fp16( (x @ W1)[r][c] * dinv[r] ), A exact via hi+lo split, W fp16 (2 MFMA/tile).
__global__ __launch_bounds__(256) void k_fg(const int* __restrict__ row, const int* __restrict__ col,
                                            int* __restrict__ cursor, unsigned short* __restrict__ esrc,
                                            const float* __restrict__ A, const uint4* __restrict__ wimg,
                                            const float* __restrict__ dinv, unsigned short* __restrict__ G) {
    __shared__ _Float16 WT[16384];  // 32 KB (fill blocks don't touch it)
    int bid = blockIdx.x;
    int t = threadIdx.x;
    if (bid >= GEMM_NB) {
        // ---- CSR fill ----
        int e = (bid - GEMM_NB) * 256 + t;
        if (e < NE) {
            int c = col[e];
            int slot = atomicAdd(&cursor[c], 1);
            esrc[slot] = (unsigned short)row[e];
        }
        return;
    }
    // ---- layer-1 GEMM ----
    {
        uint4* dst = (uint4*)&WT[0];
#pragma unroll
        for (int i = 0; i < 8; i++) dst[i * 256 + t] = wimg[i * 256 + t];
    }
    __syncthreads();
    int w = t >> 6, l = t & 63;
    int r0w = bid * 64 + w * 16;
    int lrow = l & 15, lk = l >> 4;
    int arow = r0w + lrow;

    U4H ah[4], al[4];
#pragma unroll
    for (int kk = 0; kk < 4; kk++) {
        int k0 = kk * 32 + lk * 8;
        float4 f0 = *(const float4*)&A[arow * 128 + k0];
        float4 f1 = *(const float4*)&A[arow * 128 + k0 + 4];
        float v[8] = {f0.x, f0.y, f0.z, f0.w, f1.x, f1.y, f1.z, f1.w};
#pragma unroll
        for (int j = 0; j < 8; j++) {
            _Float16 h = (_Float16)v[j];
            ah[kk].h[j] = h;
            al[kk].h[j] = (_Float16)(v[j] - (float)h);
        }
    }

    f32x4 acc[8];
#pragma unroll
    for (int ct = 0; ct < 8; ct++) acc[ct] = (f32x4){0.f, 0.f, 0.f, 0.f};

#pragma unroll
    for (int kk = 0; kk < 4; kk++) {
        int k0 = kk * 32 + lk * 8;
#pragma unroll
        for (int ct = 0; ct < 8; ct++) {
            int c = ct * 16 + lrow;
            int idx = (c * 128 + k0) ^ ((c & 7) << 3);
            U4H bh;
            bh.h = *(f16x8*)&WT[idx];
            acc[ct] = __builtin_amdgcn_mfma_f32_16x16x32_f16(ah[kk].h, bh.h, acc[ct], 0, 0, 0);
            acc[ct] = __builtin_amdgcn_mfma_f32_16x16x32_f16(al[kk].h, bh.h, acc[ct], 0, 0, 0);
        }
    }

    float dv[4];
#pragma unroll
    for (int j = 0; j < 4; j++) dv[j] = dinv[r0w + lk * 4 + j];
#pragma unroll
    for (int ct = 0; ct < 8; ct++) {
        int c = ct * 16 + lrow;
#pragma unroll
        for (int j = 0; j < 4; j++) {
            int r = r0w + lk * 4 + j;
            __half hv = __float2half(acc[ct][j] * dv[j]);
            G[r * 128 + c] = *(unsigned short*)&hv;
        }
    }
}

// ---------------- MFMA GEMM (layer 2): packed fp16 A + per-block BN finalize + ReLU ----------------
__global__ __launch_bounds__(256) void k_mgemm1(const unsigned int* __restrict__ A, const uint4* __restrict__ wimg,
                                                const float* __restrict__ slabS, const float* __restrict__ slabQ,
                                                const float* __restrict__ gamma, const float* __restrict__ beta,
                                                const float* __restrict__ dinv, unsigned short* __restrict__ G) {
    __shared__ _Float16 WT[16384];  // 32 KB
    __shared__ float ssl[256];
    int t = threadIdx.x;
    {
        uint4* dst = (uint4*)&WT[0];
#pragma unroll
        for (int i = 0; i < 8; i++) dst[i * 256 + t] = wimg[i * 256 + t];
    }
    if (t < 128) {
        float s = 0.f, q = 0.f;
        for (int b = 0; b < 64; b++) {
            s += slabS[b * 128 + t];
            q += slabQ[b * 128 + t];
        }
        float mu = s * (1.f / NN);
        float var = q * (1.f / NN) - mu * mu;
        float sc = gamma[t] * rsqrtf(var + 1e-5f);
        ssl[t] = sc;
        ssl[128 + t] = beta[t] - mu * sc;
    }
    __syncthreads();
    int w = t >> 6, l = t & 63;
    int r0w = blockIdx.x * 64 + w * 16;
    int lrow = l & 15, lk = l >> 4;
    int arow = r0w + lrow;

    U4H ah[4], al[4];
#pragma unroll
    for (int kk = 0; kk < 4; kk++) {
        int k0 = kk * 32 + lk * 8;
        uint4 u = *(const uint4*)&A[arow * 64 + (k0 >> 1)];
        unsigned int uu[4] = {u.x, u.y, u.z, u.w};
#pragma unroll
        for (int p = 0; p < 4; p++) {
            __half2 hp = *(__half2*)&uu[p];
            int k = k0 + 2 * p;
            float v0 = fmaxf(fmaf(__low2float(hp), ssl[k], ssl[128 + k]), 0.f);
            float v1 = fmaxf(fmaf(__high2float(hp), ssl[k + 1], ssl[129 + k]), 0.f);
            _Float16 h0 = (_Float16)v0;
            _Float16 h1 = (_Float16)v1;
            ah[kk].h[2 * p] = h0;
            ah[kk].h[2 * p + 1] = h1;
            al[kk].h[2 * p] = (_Float16)(v0 - (float)h0);
            al[kk].h[2 * p + 1] = (_Float16)(v1 - (float)h1);
        }
    }

    f32x4 acc[8];
#pragma unroll
    for (int ct = 0; ct < 8; ct++) acc[ct] = (f32x4){0.f, 0.f, 0.f, 0.f};

#pragma unroll
    for (int kk = 0; kk < 4; kk++) {
        int k0 = kk * 32 + lk * 8;
#pragma unroll
        for (int ct = 0; ct < 8; ct++) {
            int c = ct * 16 + lrow;
            int idx = (c * 128 + k0) ^ ((c & 7) << 3);
            U4H bh;
            bh.h = *(f16x8*)&WT[idx];
            acc[ct] = __builtin_amdgcn_mfma_f32_16x16x32_f16(ah[kk].h, bh.h, acc[ct], 0, 0, 0);
            acc[ct] = __builtin_amdgcn_mfma_f32_16x16x32_f16(al[kk].h, bh.h, acc[ct], 0, 0, 0);
        }
    }

    float dv[4];
#pragma unroll
    for (int j = 0; j < 4; j++) dv[j] = dinv[r0w + lk * 4 + j];
#pragma unroll
    for (int ct = 0; ct < 8; ct++) {
        int c = ct * 16 + lrow;
#pragma unroll
        for (int j = 0; j < 4; j++) {
            int r = r0w + lk * 4 + j;
            __half hv = __float2half(acc[ct][j] * dv[j]);
            G[r * 128 + c] = *(unsigned short*)&hv;
        }
    }
}

// ---------------- aggregation + fused BN stats (round-7 structure) ----------------
__device__ __forceinline__ void accum8(float* acc, uint4 u) {
    __half2 p0 = *(__half2*)&u.x, p1 = *(__half2*)&u.y, p2 = *(__half2*)&u.z, p3 = *(__half2*)&u.w;
    acc[0] += __low2float(p0); acc[1] += __high2float(p0);
    acc[2] += __low2float(p1); acc[3] += __high2float(p1);
    acc[4] += __low2float(p2); acc[5] += __high2float(p2);
    acc[6] += __low2float(p3); acc[7] += __high2float(p3);
}

__global__ __launch_bounds__(256) void k_agg(const uint4* __restrict__ g16, const int* __restrict__ indptr,
                                             const unsigned short* __restrict__ esrc,
                                             const float* __restrict__ dinv, const float4* __restrict__ bias4,
                                             uint4* __restrict__ hout, float* __restrict__ slabS,
                                             float* __restrict__ slabQ) {
    __shared__ float lsS[4][128];
    __shared__ float lsQ[4][128];
    int t = threadIdx.x;
    int w = t >> 6, l = t & 63;
    int slot = l >> 4, lc = l & 15;  // lane covers cols [8*lc, 8*lc+8)
    int v = blockIdx.x * 4 + w;
    int s = indptr[v], e = indptr[v + 1];
    float acc[8];
#pragma unroll
    for (int j = 0; j < 8; j++) acc[j] = 0.f;

    int i = s;
    for (; i + 15 < e; i += 16) {
        int r0 = esrc[i + slot];
        int r1 = esrc[i + 4 + slot];
        int r2 = esrc[i + 8 + slot];
        int r3 = esrc[i + 12 + slot];
        uint4 u0 = g16[r0 * 16 + lc];
        uint4 u1 = g16[r1 * 16 + lc];
        uint4 u2 = g16[r2 * 16 + lc];
        uint4 u3 = g16[r3 * 16 + lc];
        accum8(acc, u0);
        accum8(acc, u1);
        accum8(acc, u2);
        accum8(acc, u3);
    }
    for (; i + 3 < e; i += 4) {
        int r0 = esrc[i + slot];
        uint4 u0 = g16[r0 * 16 + lc];
        accum8(acc, u0);
    }
    if (i + slot < e) {
        int r0 = esrc[i + slot];
        uint4 u0 = g16[r0 * 16 + lc];
        accum8(acc, u0);
    }
    // cross-slot reduce
#pragma unroll
    for (int j = 0; j < 8; j++) {
        acc[j] += __shfl_xor(acc[j], 16, 64);
        acc[j] += __shfl_xor(acc[j], 32, 64);
    }
    if (l < 16) {
        uint4 us = g16[v * 16 + l];  // self-loop
        accum8(acc, us);
        float dvv = dinv[v];
        float4 ba = bias4[2 * l];
        float4 bb = bias4[2 * l + 1];
        float vv[8];
        vv[0] = acc[0] * dvv + ba.x; vv[1] = acc[1] * dvv + ba.y;
        vv[2] = acc[2] * dvv + ba.z; vv[3] = acc[3] * dvv + ba.w;
        vv[4] = acc[4] * dvv + bb.x; vv[5] = acc[5] * dvv + bb.y;
        vv[6] = acc[6] * dvv + bb.z; vv[7] = acc[7] * dvv + bb.w;
        __half2 h0 = __floats2half2_rn(vv[0], vv[1]);
        __half2 h1 = __floats2half2_rn(vv[2], vv[3]);
        __half2 h2 = __floats2half2_rn(vv[4], vv[5]);
        __half2 h3 = __floats2half2_rn(vv[6], vv[7]);
        uint4 o;
        o.x = *(unsigned int*)&h0; o.y = *(unsigned int*)&h1;
        o.z = *(unsigned int*)&h2; o.w = *(unsigned int*)&h3;
        hout[v * 16 + l] = o;
#pragma unroll
        for (int j = 0; j < 8; j++) {
            lsS[w][l * 8 + j] = vv[j];
            lsQ[w][l * 8 + j] = vv[j] * vv[j];
        }
    }
    __syncthreads();
    int sb = (blockIdx.x & 63) * 128;
    if (t < 128) {
        atomicAdd(&slabS[sb + t], (lsS[0][t] + lsS[1][t]) + (lsS[2][t] + lsS[3][t]));
    } else {
        int c = t - 128;
        atomicAdd(&slabQ[sb + c], (lsQ[0][c] + lsQ[1][c]) + (lsQ[2][c] + lsQ[3][c]));
    }
}

// ---------------- pooling: per-block BN finalize + pooled[g][c] += relu(bn2(h16)) ----------------
__global__ __launch_bounds__(256) void k_pool(const unsigned int* __restrict__ h, const int* __restrict__ batch,
                                              const float* __restrict__ slabS, const float* __restrict__ slabQ,
                                              const float* __restrict__ gamma, const float* __restrict__ beta,
                                              float* __restrict__ pooled) {
    __shared__ float ssl[256];
    int t = threadIdx.x;
    if (t < 128) {
        float s = 0.f, q = 0.f;
        for (int b = 0; b < 64; b++) {
            s += slabS[b * 128 + t];
            q += slabQ[b * 128 + t];
        }
        float mu = s * (1.f / NN);
        float var = q * (1.f / NN) - mu * mu;
        float sc = gamma[t] * rsqrtf(var + 1e-5f);
        ssl[t] = sc;
        ssl[128 + t] = beta[t] - mu * sc;
    }
    __syncthreads();
    int c2 = t & 63, q = t >> 6;
    float sc0 = ssl[2 * c2], sc1 = ssl[2 * c2 + 1];
    float sh0 = ssl[128 + 2 * c2], sh1 = ssl[129 + 2 * c2];
    int r0 = blockIdx.x * 64;
    int g_cur = -1;
    float a0 = 0.f, a1 = 0.f;
    for (int i = 0; i < 16; i++) {
        int r = r0 + q + 4 * i;
        int g = batch[r];
        unsigned int u = h[r * 64 + c2];
        __half2 p = *(__half2*)&u;
        float v0 = fmaxf(fmaf(__low2float(p), sc0, sh0), 0.f);
        float v1 = fmaxf(fmaf(__high2float(p), sc1, sh1), 0.f);
        if (g != g_cur) {
            if (g_cur >= 0) {
                atomicAdd(&pooled[g_cur * 128 + 2 * c2], a0);
                atomicAdd(&pooled[g_cur * 128 + 2 * c2 + 1], a1);
            }
            a0 = 0.f; a1 = 0.f; g_cur = g;
        }
        a0 += v0; a1 += v1;
    }
    if (g_cur >= 0) {
        atomicAdd(&pooled[g_cur * 128 + 2 * c2], a0);
        atomicAdd(&pooled[g_cur * 128 + 2 * c2 + 1], a1);
    }
}

// ---------------- head ----------------
__global__ __launch_bounds__(256) void k_head(const float* __restrict__ pooled, const int* __restrict__ gstart,
                                              const int* __restrict__ gend, const float* __restrict__ l1W,
                                              const float* __restrict__ l1b, const float* __restrict__ l2W,
                                              const float* __restrict__ l2b, float* __restrict__ out) {
    __shared__ float P[64 * 128];
    __shared__ float Z[64 * 64];
    int t = threadIdx.x;
    for (int i = t; i < 64 * 128; i += 256) {
        int g = i >> 7;
        float cnt = (float)max(gend[g] - gstart[g], 1);
        P[i] = pooled[i] / cnt;
    }
    __syncthreads();
    for (int o = t; o < 64 * 64; o += 256) {
        int g = o >> 6, j = o & 63;
        float s = l1b[j];
        for (int k = 0; k < 128; k++) s += P[g * 128 + k] * l1W[k * 64 + j];
        Z[o] = fmaxf(s, 0.f);
    }
    __syncthreads();
    if (t < 128) {
        int g = t >> 1, cls = t & 1;
        float s = l2b[cls];
        for (int k = 0; k < 64; k++) s += Z[g * 64 + k] * l2W[k * 2 + cls];
        out[g * 2 + cls] = s;
    }
}

extern "C" void kernel_launch(void* const* d_in, const int* in_sizes, int n_in, void* d_out, int out_size,
                              void* d_ws, size_t ws_size, hipStream_t stream) {
    (void)in_sizes; (void)n_in; (void)out_size; (void)ws_size;
    const float* x = (const float*)d_in[0];
    const int* ei = (const int*)d_in[1];
    const int* row = ei;
    const int* col = ei + NE;
    const int* batch = (const int*)d_in[2];
    const float* W1 = (const float*)d_in[3];
    const float* b1 = (const float*)d_in[4];
    const float* W2 = (const float*)d_in[5];
    const float* b2 = (const float*)d_in[6];
    const float* g1 = (const float*)d_in[7];
    const float* be1 = (const float*)d_in[8];
    const float* g2 = (const float*)d_in[9];
    const float* be2 = (const float*)d_in[10];
    const float* l1W = (const float*)d_in[11];
    const float* l1b = (const float*)d_in[12];
    const float* l2W = (const float*)d_in[13];
    const float* l2b = (const float*)d_in[14];
    float* out = (float*)d_out;

    char* ws = (char*)d_ws;
    size_t off = 0;
    auto alloc = [&](size_t bytes) {
        void* p = ws + off;
        off += (bytes + 255) & ~(size_t)255;
        return p;
    };
    unsigned int* g16 = (unsigned int*)alloc(NN * 64 * 4);   // packed fp16 (h*dinv), row-major 128 cols
    unsigned int* h16a = (unsigned int*)alloc(NN * 64 * 4);  // layer-1 agg out fp16
    unsigned int* h16b = (unsigned int*)alloc(NN * 64 * 4);  // layer-2 agg out fp16
    int* deg = (int*)alloc(NN * 4);
    float* dinv = (float*)alloc(NN * 4);
    int* indptr = (int*)alloc((NN + 1) * 4);
    int* cursor = (int*)alloc(NN * 4);
    unsigned short* esrc = (unsigned short*)alloc(NE * 2);
    int* partial = (int*)alloc(256 * 4);
    float* slabs = (float*)alloc(4 * 8192 * 4);  // S1,Q1,S2,Q2
    float* pooled = (float*)alloc(NG * F * 4);
    int* gstart = (int*)alloc(NG * 4);
    int* gend = (int*)alloc(NG * 4);
    _Float16* wimg1 = (_Float16*)alloc(16384 * 2);
    _Float16* wimg2 = (_Float16*)alloc(16384 * 2);

    float* slab1S = slabs;
    float* slab1Q = slabs + 8192;
    float* slab2S = slabs + 16384;
    float* slab2Q = slabs + 24576;

    k_init<<<SCAN_NB, 256, 0, stream>>>(batch, deg, pooled, slabs, gstart, gend, W1, W2, wimg1, wimg2);
    k_deg<<<NE / 256, 256, 0, stream>>>(col, deg);
    k_scan1<<<SCAN_NB, 256, 0, stream>>>(deg, partial);
    k_scan3<<<SCAN_NB, 256, 0, stream>>>(deg, partial, indptr, cursor, dinv);

    // fat kernel: layer-1 GEMM (blocks 0..624) + CSR fill (blocks 625..3124)
    k_fg<<<GEMM_NB + NE / 256, 256, 0, stream>>>(row, col, cursor, esrc, x, (const uint4*)wimg1, dinv,
                                                 (unsigned short*)g16);

    // layer 1 aggregation
    k_agg<<<NN / 4, 256, 0, stream>>>((const uint4*)g16, indptr, esrc, dinv, (const float4*)b1, (uint4*)h16a,
                                      slab1S, slab1Q);

    // layer 2 (BN1 finalize + ReLU fused into GEMM A-load)
    k_mgemm1<<<GEMM_NB, 256, 0, stream>>>(h16a, (const uint4*)wimg2, slab1S, slab1Q, g1, be1, dinv,
                                          (unsigned short*)g16);
    k_agg<<<NN / 4, 256, 0, stream>>>((const uint4*)g16, indptr, esrc, dinv, (const float4*)b2, (uint4*)h16b,
                                      slab2S, slab2Q);

    // pooling (BN2 finalize fused) + head
    k_pool<<<NN / 64, 256, 0, stream>>>(h16b, batch, slab2S, slab2Q, g2, be2, pooled);
    k_head<<<1, 256, 0, stream>>>(pooled, gstart, gend, l1W, l1b, l2W, l2b, out);
}

// Round 11
// 187.994 us; speedup vs baseline: 1.0195x; 1.0195x over previous
//
#include <hip/hip_runtime.h>
#include <hip/hip_fp16.h>

#define NN 40000
#define NE 640000
#define F 128
#define NG 64
#define SCAN_NB 157  // ceil(40000/256)
#define GEMM_NB 625  // NN/64

typedef _Float16 f16x8 __attribute__((ext_vector_type(8)));
typedef float f32x4 __attribute__((ext_vector_type(4)));

union U4H {
    uint4 u;
    f16x8 h;
};

// ---------------- init: zero deg/pooled/slabs + graph bounds + W fp16 prep ----------------
__global__ __launch_bounds__(256) void k_init(const int* __restrict__ batch, int* __restrict__ deg,
                                              float* __restrict__ pooled, float* __restrict__ slabs,
                                              int* __restrict__ gstart, int* __restrict__ gend,
                                              const float* __restrict__ W1, const float* __restrict__ W2,
                                              _Float16* __restrict__ img1, _Float16* __restrict__ img2) {
    int i = blockIdx.x * 256 + threadIdx.x;
    if (i < NN) {
        deg[i] = 0;
        int g = batch[i];
        if (i == 0 || batch[i - 1] != g) gstart[g] = i;
        if (i == NN - 1 || batch[i + 1] != g) gend[g] = i + 1;
    }
    if (i < NG * F) pooled[i] = 0.f;
    if (i < 32768) {
        slabs[i] = 0.f;  // S1,Q1,S2,Q2 (4 x 8192)
        // W prep: fp16 round, transposed + XOR-swizzled image (A split exactly; only W rounds)
        const float* W = (i < 16384) ? W1 : W2;
        _Float16* img = (i < 16384) ? img1 : img2;
        int j = i & 16383;
        int k = j >> 7, c = j & 127;
        int idx = (c * 128 + k) ^ ((c & 7) << 3);
        img[idx] = (_Float16)W[j];
    }
}

// ---------------- degree histogram ----------------
__global__ __launch_bounds__(256) void k_deg(const int* __restrict__ col, int* __restrict__ deg) {
    int e = blockIdx.x * 256 + threadIdx.x;
    if (e < NE) atomicAdd(&deg[col[e]], 1);
}

// ---------------- scan phase 1: per-block sums ----------------
__global__ __launch_bounds__(256) void k_scan1(const int* __restrict__ deg, int* __restrict__ partial) {
    __shared__ int sp[256];
    int t = threadIdx.x;
    int i = blockIdx.x * 256 + t;
    sp[t] = (i < NN) ? deg[i] : 0;
    __syncthreads();
#pragma unroll
    for (int off = 128; off > 0; off >>= 1) {
        if (t < off) sp[t] += sp[t + off];
        __syncthreads();
    }
    if (t == 0) partial[blockIdx.x] = sp[0];
}

// ---------------- scan phase 2 (fused): every block scans partials + local scan ----------------
__global__ __launch_bounds__(256) void k_scan3(const int* __restrict__ deg, const int* __restrict__ partial,
                                               int* __restrict__ indptr, int* __restrict__ cursor,
                                               float* __restrict__ dinv) {
    __shared__ int sp[256];
    __shared__ int sd[256];
    int t = threadIdx.x;
    sp[t] = (t < SCAN_NB) ? partial[t] : 0;
    __syncthreads();
#pragma unroll
    for (int off = 1; off < 256; off <<= 1) {
        int add = (t >= off) ? sp[t - off] : 0;
        __syncthreads();
        sp[t] += add;
        __syncthreads();
    }
    int bid = blockIdx.x;
    if (bid == 0 && t == 0) indptr[NN] = sp[SCAN_NB - 1];
    int bsum = (bid == 0) ? 0 : sp[bid - 1];

    int i = bid * 256 + t;
    int d = (i < NN) ? deg[i] : 0;
    sd[t] = d;
    __syncthreads();
#pragma unroll
    for (int off = 1; off < 256; off <<= 1) {
        int add = (t >= off) ? sd[t - off] : 0;
        __syncthreads();
        sd[t] += add;
        __syncthreads();
    }
    if (i < NN) {
        int excl = bsum + sd[t] - d;
        indptr[i] = excl;
        cursor[i] = excl;
        dinv[i] = rsqrtf((float)(d + 1));
    }
}

// ---------------- CSR fill (standalone, ushort sources) ----------------
__global__ __launch_bounds__(256) void k_fill(const int* __restrict__ row, const int* __restrict__ col,
                                              int* __restrict__ cursor, unsigned short* __restrict__ esrc) {
    int e = blockIdx.x * 256 + threadIdx.x;
    if (e < NE) {
        int c = col[e];
        int slot = atomicAdd(&cursor[c], 1);
        esrc[slot] = (unsigned short)row[e];
    }
}

// ---------------- MFMA GEMM (layer 1): A fp32 exact hi+lo split, W fp16 (2 MFMA/tile) ----------------
__global__ __launch_bounds__(256) void k_mgemm0(const float* __restrict__ A, const uint4* __restrict__ wimg,
                                                const float* __restrict__ dinv, unsigned short* __restrict__ G) {
    __shared__ _Float16 WT[16384];  // 32 KB
    int t = threadIdx.x;
    {
        uint4* dst = (uint4*)&WT[0];
#pragma unroll
        for (int i = 0; i < 8; i++) dst[i * 256 + t] = wimg[i * 256 + t];
    }
    __syncthreads();
    int w = t >> 6, l = t & 63;
    int r0w = blockIdx.x * 64 + w * 16;
    int lrow = l & 15, lk = l >> 4;
    int arow = r0w + lrow;

    U4H ah[4], al[4];
#pragma unroll
    for (int kk = 0; kk < 4; kk++) {
        int k0 = kk * 32 + lk * 8;
        float4 f0 = *(const float4*)&A[arow * 128 + k0];
        float4 f1 = *(const float4*)&A[arow * 128 + k0 + 4];
        float v[8] = {f0.x, f0.y, f0.z, f0.w, f1.x, f1.y, f1.z, f1.w};
#pragma unroll
        for (int j = 0; j < 8; j++) {
            _Float16 h = (_Float16)v[j];
            ah[kk].h[j] = h;
            al[kk].h[j] = (_Float16)(v[j] - (float)h);
        }
    }

    f32x4 acc[8];
#pragma unroll
    for (int ct = 0; ct < 8; ct++) acc[ct] = (f32x4){0.f, 0.f, 0.f, 0.f};

#pragma unroll
    for (int kk = 0; kk < 4; kk++) {
        int k0 = kk * 32 + lk * 8;
#pragma unroll
        for (int ct = 0; ct < 8; ct++) {
            int c = ct * 16 + lrow;
            int idx = (c * 128 + k0) ^ ((c & 7) << 3);
            U4H bh;
            bh.h = *(f16x8*)&WT[idx];
            acc[ct] = __builtin_amdgcn_mfma_f32_16x16x32_f16(ah[kk].h, bh.h, acc[ct], 0, 0, 0);
            acc[ct] = __builtin_amdgcn_mfma_f32_16x16x32_f16(al[kk].h, bh.h, acc[ct], 0, 0, 0);
        }
    }

    float dv[4];
#pragma unroll
    for (int j = 0; j < 4; j++) dv[j] = dinv[r0w + lk * 4 + j];
#pragma unroll
    for (int ct = 0; ct < 8; ct++) {
        int c = ct * 16 + lrow;
#pragma unroll
        for (int j = 0; j < 4; j++) {
            int r = r0w + lk * 4 + j;
            __half hv = __float2half(acc[ct][j] * dv[j]);
            G[r * 128 + c] = *(unsigned short*)&hv;
        }
    }
}

// ---------------- MFMA GEMM (layer 2): packed fp16 A + per-block BN finalize + ReLU ----------------
__global__ __launch_bounds__(256) void k_mgemm1(const unsigned int* __restrict__ A, const uint4* __restrict__ wimg,
                                                const float* __restrict__ slabS, const float* __restrict__ slabQ,
                                                const float* __restrict__ gamma, const float* __restrict__ beta,
                                                const float* __restrict__ dinv, unsigned short* __restrict__ G) {
    __shared__ _Float16 WT[16384];  // 32 KB
    __shared__ float ssl[256];
    int t = threadIdx.x;
    {
        uint4* dst = (uint4*)&WT[0];
#pragma unroll
        for (int i = 0; i < 8; i++) dst[i * 256 + t] = wimg[i * 256 + t];
    }
    if (t < 128) {
        float s = 0.f, q = 0.f;
        for (int b = 0; b < 64; b++) {
            s += slabS[b * 128 + t];
            q += slabQ[b * 128 + t];
        }
        float mu = s * (1.f / NN);
        float var = q * (1.f / NN) - mu * mu;
        float sc = gamma[t] * rsqrtf(var + 1e-5f);
        ssl[t] = sc;
        ssl[128 + t] = beta[t] - mu * sc;
    }
    __syncthreads();
    int w = t >> 6, l = t & 63;
    int r0w = blockIdx.x * 64 + w * 16;
    int lrow = l & 15, lk = l >> 4;
    int arow = r0w + lrow;

    U4H ah[4], al[4];
#pragma unroll
    for (int kk = 0; kk < 4; kk++) {
        int k0 = kk * 32 + lk * 8;
        uint4 u = *(const uint4*)&A[arow * 64 + (k0 >> 1)];
        unsigned int uu[4] = {u.x, u.y, u.z, u.w};
#pragma unroll
        for (int p = 0; p < 4; p++) {
            __half2 hp = *(__half2*)&uu[p];
            int k = k0 + 2 * p;
            float v0 = fmaxf(fmaf(__low2float(hp), ssl[k], ssl[128 + k]), 0.f);
            float v1 = fmaxf(fmaf(__high2float(hp), ssl[k + 1], ssl[129 + k]), 0.f);
            _Float16 h0 = (_Float16)v0;
            _Float16 h1 = (_Float16)v1;
            ah[kk].h[2 * p] = h0;
            ah[kk].h[2 * p + 1] = h1;
            al[kk].h[2 * p] = (_Float16)(v0 - (float)h0);
            al[kk].h[2 * p + 1] = (_Float16)(v1 - (float)h1);
        }
    }

    f32x4 acc[8];
#pragma unroll
    for (int ct = 0; ct < 8; ct++) acc[ct] = (f32x4){0.f, 0.f, 0.f, 0.f};

#pragma unroll
    for (int kk = 0; kk < 4; kk++) {
        int k0 = kk * 32 + lk * 8;
#pragma unroll
        for (int ct = 0; ct < 8; ct++) {
            int c = ct * 16 + lrow;
            int idx = (c * 128 + k0) ^ ((c & 7) << 3);
            U4H bh;
            bh.h = *(f16x8*)&WT[idx];
            acc[ct] = __builtin_amdgcn_mfma_f32_16x16x32_f16(ah[kk].h, bh.h, acc[ct], 0, 0, 0);
            acc[ct] = __builtin_amdgcn_mfma_f32_16x16x32_f16(al[kk].h, bh.h, acc[ct], 0, 0, 0);
        }
    }

    float dv[4];
#pragma unroll
    for (int j = 0; j < 4; j++) dv[j] = dinv[r0w + lk * 4 + j];
#pragma unroll
    for (int ct = 0; ct < 8; ct++) {
        int c = ct * 16 + lrow;
#pragma unroll
        for (int j = 0; j < 4; j++) {
            int r = r0w + lk * 4 + j;
            __half hv = __float2half(acc[ct][j] * dv[j]);
            G[r * 128 + c] = *(unsigned short*)&hv;
        }
    }
}

// ---------------- aggregation + fused BN stats (round-7 structure) ----------------
__device__ __forceinline__ void accum8(float* acc, uint4 u) {
    __half2 p0 = *(__half2*)&u.x, p1 = *(__half2*)&u.y, p2 = *(__half2*)&u.z, p3 = *(__half2*)&u.w;
    acc[0] += __low2float(p0); acc[1] += __high2float(p0);
    acc[2] += __low2float(p1); acc[3] += __high2float(p1);
    acc[4] += __low2float(p2); acc[5] += __high2float(p2);
    acc[6] += __low2float(p3); acc[7] += __high2float(p3);
}

__global__ __launch_bounds__(256) void k_agg(const uint4* __restrict__ g16, const int* __restrict__ indptr,
                                             const unsigned short* __restrict__ esrc,
                                             const float* __restrict__ dinv, const float4* __restrict__ bias4,
                                             uint4* __restrict__ hout, float* __restrict__ slabS,
                                             float* __restrict__ slabQ) {
    __shared__ float lsS[4][128];
    __shared__ float lsQ[4][128];
    int t = threadIdx.x;
    int w = t >> 6, l = t & 63;
    int slot = l >> 4, lc = l & 15;  // lane covers cols [8*lc, 8*lc+8)
    int v = blockIdx.x * 4 + w;
    int s = indptr[v], e = indptr[v + 1];
    float acc[8];
#pragma unroll
    for (int j = 0; j < 8; j++) acc[j] = 0.f;

    int i = s;
    for (; i + 15 < e; i += 16) {
        int r0 = esrc[i + slot];
        int r1 = esrc[i + 4 + slot];
        int r2 = esrc[i + 8 + slot];
        int r3 = esrc[i + 12 + slot];
        uint4 u0 = g16[r0 * 16 + lc];
        uint4 u1 = g16[r1 * 16 + lc];
        uint4 u2 = g16[r2 * 16 + lc];
        uint4 u3 = g16[r3 * 16 + lc];
        accum8(acc, u0);
        accum8(acc, u1);
        accum8(acc, u2);
        accum8(acc, u3);
    }
    for (; i + 3 < e; i += 4) {
        int r0 = esrc[i + slot];
        uint4 u0 = g16[r0 * 16 + lc];
        accum8(acc, u0);
    }
    if (i + slot < e) {
        int r0 = esrc[i + slot];
        uint4 u0 = g16[r0 * 16 + lc];
        accum8(acc, u0);
    }
    // cross-slot reduce
#pragma unroll
    for (int j = 0; j < 8; j++) {
        acc[j] += __shfl_xor(acc[j], 16, 64);
        acc[j] += __shfl_xor(acc[j], 32, 64);
    }
    if (l < 16) {
        uint4 us = g16[v * 16 + l];  // self-loop
        accum8(acc, us);
        float dvv = dinv[v];
        float4 ba = bias4[2 * l];
        float4 bb = bias4[2 * l + 1];
        float vv[8];
        vv[0] = acc[0] * dvv + ba.x; vv[1] = acc[1] * dvv + ba.y;
        vv[2] = acc[2] * dvv + ba.z; vv[3] = acc[3] * dvv + ba.w;
        vv[4] = acc[4] * dvv + bb.x; vv[5] = acc[5] * dvv + bb.y;
        vv[6] = acc[6] * dvv + bb.z; vv[7] = acc[7] * dvv + bb.w;
        __half2 h0 = __floats2half2_rn(vv[0], vv[1]);
        __half2 h1 = __floats2half2_rn(vv[2], vv[3]);
        __half2 h2 = __floats2half2_rn(vv[4], vv[5]);
        __half2 h3 = __floats2half2_rn(vv[6], vv[7]);
        uint4 o;
        o.x = *(unsigned int*)&h0; o.y = *(unsigned int*)&h1;
        o.z = *(unsigned int*)&h2; o.w = *(unsigned int*)&h3;
        hout[v * 16 + l] = o;
#pragma unroll
        for (int j = 0; j < 8; j++) {
            lsS[w][l * 8 + j] = vv[j];
            lsQ[w][l * 8 + j] = vv[j] * vv[j];
        }
    }
    __syncthreads();
    int sb = (blockIdx.x & 63) * 128;
    if (t < 128) {
        atomicAdd(&slabS[sb + t], (lsS[0][t] + lsS[1][t]) + (lsS[2][t] + lsS[3][t]));
    } else {
        int c = t - 128;
        atomicAdd(&slabQ[sb + c], (lsQ[0][c] + lsQ[1][c]) + (lsQ[2][c] + lsQ[3][c]));
    }
}

// ---------------- pooling: per-block BN finalize + pooled[g][c] += relu(bn2(h16)) ----------------
__global__ __launch_bounds__(256) void k_pool(const unsigned int* __restrict__ h, const int* __restrict__ batch,
                                              const float* __restrict__ slabS, const float* __restrict__ slabQ,
                                              const float* __restrict__ gamma, const float* __restrict__ beta,
                                              float* __restrict__ pooled) {
    __shared__ float ssl[256];
    int t = threadIdx.x;
    if (t < 128) {
        float s = 0.f, q = 0.f;
        for (int b = 0; b < 64; b++) {
            s += slabS[b * 128 + t];
            q += slabQ[b * 128 + t];
        }
        float mu = s * (1.f / NN);
        float var = q * (1.f / NN) - mu * mu;
        float sc = gamma[t] * rsqrtf(var + 1e-5f);
        ssl[t] = sc;
        ssl[128 + t] = beta[t] - mu * sc;
    }
    __syncthreads();
    int c2 = t & 63, q = t >> 6;
    float sc0 = ssl[2 * c2], sc1 = ssl[2 * c2 + 1];
    float sh0 = ssl[128 + 2 * c2], sh1 = ssl[129 + 2 * c2];
    int r0 = blockIdx.x * 64;
    int g_cur = -1;
    float a0 = 0.f, a1 = 0.f;
    for (int i = 0; i < 16; i++) {
        int r = r0 + q + 4 * i;
        int g = batch[r];
        unsigned int u = h[r * 64 + c2];
        __half2 p = *(__half2*)&u;
        float v0 = fmaxf(fmaf(__low2float(p), sc0, sh0), 0.f);
        float v1 = fmaxf(fmaf(__high2float(p), sc1, sh1), 0.f);
        if (g != g_cur) {
            if (g_cur >= 0) {
                atomicAdd(&pooled[g_cur * 128 + 2 * c2], a0);
                atomicAdd(&pooled[g_cur * 128 + 2 * c2 + 1], a1);
            }
            a0 = 0.f; a1 = 0.f; g_cur = g;
        }
        a0 += v0; a1 += v1;
    }
    if (g_cur >= 0) {
        atomicAdd(&pooled[g_cur * 128 + 2 * c2], a0);
        atomicAdd(&pooled[g_cur * 128 + 2 * c2 + 1], a1);
    }
}

// ---------------- head ----------------
__global__ __launch_bounds__(256) void k_head(const float* __restrict__ pooled, const int* __restrict__ gstart,
                                              const int* __restrict__ gend, const float* __restrict__ l1W,
                                              const float* __restrict__ l1b, const float* __restrict__ l2W,
                                              const float* __restrict__ l2b, float* __restrict__ out) {
    __shared__ float P[64 * 128];
    __shared__ float Z[64 * 64];
    int t = threadIdx.x;
    for (int i = t; i < 64 * 128; i += 256) {
        int g = i >> 7;
        float cnt = (float)max(gend[g] - gstart[g], 1);
        P[i] = pooled[i] / cnt;
    }
    __syncthreads();
    for (int o = t; o < 64 * 64; o += 256) {
        int g = o >> 6, j = o & 63;
        float s = l1b[j];
        for (int k = 0; k < 128; k++) s += P[g * 128 + k] * l1W[k * 64 + j];
        Z[o] = fmaxf(s, 0.f);
    }
    __syncthreads();
    if (t < 128) {
        int g = t >> 1, cls = t & 1;
        float s = l2b[cls];
        for (int k = 0; k < 64; k++) s += Z[g * 64 + k] * l2W[k * 2 + cls];
        out[g * 2 + cls] = s;
    }
}

extern "C" void kernel_launch(void* const* d_in, const int* in_sizes, int n_in, void* d_out, int out_size,
                              void* d_ws, size_t ws_size, hipStream_t stream) {
    (void)in_sizes; (void)n_in; (void)out_size; (void)ws_size;
    const float* x = (const float*)d_in[0];
    const int* ei = (const int*)d_in[1];
    const int* row = ei;
    const int* col = ei + NE;
    const int* batch = (const int*)d_in[2];
    const float* W1 = (const float*)d_in[3];
    const float* b1 = (const float*)d_in[4];
    const float* W2 = (const float*)d_in[5];
    const float* b2 = (const float*)d_in[6];
    const float* g1 = (const float*)d_in[7];
    const float* be1 = (const float*)d_in[8];
    const float* g2 = (const float*)d_in[9];
    const float* be2 = (const float*)d_in[10];
    const float* l1W = (const float*)d_in[11];
    const float* l1b = (const float*)d_in[12];
    const float* l2W = (const float*)d_in[13];
    const float* l2b = (const float*)d_in[14];
    float* out = (float*)d_out;

    char* ws = (char*)d_ws;
    size_t off = 0;
    auto alloc = [&](size_t bytes) {
        void* p = ws + off;
        off += (bytes + 255) & ~(size_t)255;
        return p;
    };
    unsigned int* g16 = (unsigned int*)alloc(NN * 64 * 4);   // packed fp16 (h*dinv), row-major 128 cols
    unsigned int* h16a = (unsigned int*)alloc(NN * 64 * 4);  // layer-1 agg out fp16
    unsigned int* h16b = (unsigned int*)alloc(NN * 64 * 4);  // layer-2 agg out fp16
    int* deg = (int*)alloc(NN * 4);
    float* dinv = (float*)alloc(NN * 4);
    int* indptr = (int*)alloc((NN + 1) * 4);
    int* cursor = (int*)alloc(NN * 4);
    unsigned short* esrc = (unsigned short*)alloc(NE * 2);
    int* partial = (int*)alloc(256 * 4);
    float* slabs = (float*)alloc(4 * 8192 * 4);  // S1,Q1,S2,Q2
    float* pooled = (float*)alloc(NG * F * 4);
    int* gstart = (int*)alloc(NG * 4);
    int* gend = (int*)alloc(NG * 4);
    _Float16* wimg1 = (_Float16*)alloc(16384 * 2);
    _Float16* wimg2 = (_Float16*)alloc(16384 * 2);

    float* slab1S = slabs;
    float* slab1Q = slabs + 8192;
    float* slab2S = slabs + 16384;
    float* slab2Q = slabs + 24576;

    k_init<<<SCAN_NB, 256, 0, stream>>>(batch, deg, pooled, slabs, gstart, gend, W1, W2, wimg1, wimg2);
    k_deg<<<NE / 256, 256, 0, stream>>>(col, deg);
    k_scan1<<<SCAN_NB, 256, 0, stream>>>(deg, partial);
    k_scan3<<<SCAN_NB, 256, 0, stream>>>(deg, partial, indptr, cursor, dinv);
    k_fill<<<NE / 256, 256, 0, stream>>>(row, col, cursor, esrc);

    // layer 1
    k_mgemm0<<<GEMM_NB, 256, 0, stream>>>(x, (const uint4*)wimg1, dinv, (unsigned short*)g16);
    k_agg<<<NN / 4, 256, 0, stream>>>((const uint4*)g16, indptr, esrc, dinv, (const float4*)b1, (uint4*)h16a,
                                      slab1S, slab1Q);

    // layer 2 (BN1 finalize + ReLU fused into GEMM A-load)
    k_mgemm1<<<GEMM_NB, 256, 0, stream>>>(h16a, (const uint4*)wimg2, slab1S, slab1Q, g1, be1, dinv,
                                          (unsigned short*)g16);
    k_agg<<<NN / 4, 256, 0, stream>>>((const uint4*)g16, indptr, esrc, dinv, (const float4*)b2, (uint4*)h16b,
                                      slab2S, slab2Q);

    // pooling (BN2 finalize fused) + head
    k_pool<<<NN / 64, 256, 0, stream>>>(h16b, batch, slab2S, slab2Q, g2, be2, pooled);
    k_head<<<1, 256, 0, stream>>>(pooled, gstart, gend, l1W, l1b, l2W, l2b, out);
}